// Round 7
// baseline (323.212 us; speedup 1.0000x reference)
//
#include <hip/hip_runtime.h>

#define NN 50000
#define NE 800000
#define D  128

typedef _Float16 f16;
typedef _Float16 f16x4 __attribute__((ext_vector_type(4)));
typedef _Float16 f16x8 __attribute__((ext_vector_type(8)));
typedef float f32x4 __attribute__((ext_vector_type(4)));
typedef float f32x2 __attribute__((ext_vector_type(2)));
typedef unsigned short u16;
typedef unsigned int u32;
typedef unsigned char u8;

// ---------------- prep: f32->f16 + f32->fp8 converts + deg zeroing ----------------
// blocks [0,6250): x -> xf (f16) and xf8 (fp8); [6250,6346): 6 weight mats; rest: zero deg
__global__ __launch_bounds__(256) void prep(
    const float* __restrict__ x, f16* __restrict__ xf, u8* __restrict__ xf8,
    const float* w0, const float* w1, const float* w2,
    const float* w3, const float* w4, const float* w5,
    f16* d0, f16* d1, f16* d2, f16* d3, f16* d4, f16* d5,
    int* __restrict__ deg) {
    int b = blockIdx.x;
    if (b < 6250) {
        int i = b * 256 + threadIdx.x;
        float4 v = ((const float4*)x)[i];
        f16x4 o = {(f16)v.x, (f16)v.y, (f16)v.z, (f16)v.w};
        ((f16x4*)xf)[i] = o;
        u32 lo = __builtin_amdgcn_cvt_pk_fp8_f32(v.x, v.y, 0, false);
        u32 pk = __builtin_amdgcn_cvt_pk_fp8_f32(v.z, v.w, lo, true);
        ((u32*)xf8)[i] = pk;
    } else if (b < 6346) {
        int wb = b - 6250;
        int mat = wb >> 4;
        const float* s; f16* d;
        switch (mat) {
            case 0: s = w0; d = d0; break; case 1: s = w1; d = d1; break;
            case 2: s = w2; d = d2; break; case 3: s = w3; d = d3; break;
            case 4: s = w4; d = d4; break; default: s = w5; d = d5; break;
        }
        int i = (wb & 15) * 256 + threadIdx.x;   // 0..4095 float4
        float4 v = ((const float4*)s)[i];
        f16x4 o = {(f16)v.x, (f16)v.y, (f16)v.z, (f16)v.w};
        ((f16x4*)d)[i] = o;
    } else {
        int i = (b - 6346) * 256 + threadIdx.x;
        if (i < NN) deg[i] = 0;
    }
}

// ---------------- CSR build ----------------

__global__ __launch_bounds__(256) void count_deg_rank(
    const int* __restrict__ row, int* __restrict__ deg, u16* __restrict__ rank, int e2) {
    int i = blockIdx.x * blockDim.x + threadIdx.x;
    if (i < e2) {
        int2 r = ((const int2*)row)[i];
        unsigned ra = (unsigned)atomicAdd(&deg[r.x], 1);
        unsigned rb = (unsigned)atomicAdd(&deg[r.y], 1);
        ((unsigned*)rank)[i] = (ra & 0xffffu) | (rb << 16);
    }
}

// single-kernel scan: each block redundantly reduces its prefix (deg is L2-resident)
__global__ void scan_offsets(const int* __restrict__ deg, int* __restrict__ offsets, int n) {
    __shared__ int s[1024];
    int lim = blockIdx.x << 10;
    int a = 0;
    for (int i = threadIdx.x; i < lim; i += 1024) a += deg[i];
    s[threadIdx.x] = a;
    __syncthreads();
    for (int off = 512; off > 0; off >>= 1) {
        if (threadIdx.x < off) s[threadIdx.x] += s[threadIdx.x + off];
        __syncthreads();
    }
    int base = s[0];
    __syncthreads();
    int i = lim + threadIdx.x;
    int dv = (i < n) ? deg[i] : 0;
    s[threadIdx.x] = dv;
    __syncthreads();
    for (int off = 1; off < 1024; off <<= 1) {
        int t = (threadIdx.x >= (unsigned)off) ? s[threadIdx.x - off] : 0;
        __syncthreads();
        s[threadIdx.x] += t;
        __syncthreads();
    }
    if (i < n) {
        offsets[i + 1] = s[threadIdx.x] + base;
        if (i == 0) offsets[0] = 0;
    }
}

__global__ __launch_bounds__(256) void fill_csr(
    const int* __restrict__ row, const int* __restrict__ col,
    const u16* __restrict__ rank, const int* __restrict__ offsets,
    u16* __restrict__ csr_col, int e2) {
    int i = blockIdx.x * blockDim.x + threadIdx.x;
    if (i < e2) {
        int2 r = ((const int2*)row)[i];
        int2 c = ((const int2*)col)[i];
        unsigned rk = ((const unsigned*)rank)[i];
        csr_col[offsets[r.x] + (int)(rk & 0xffffu)] = (u16)c.x;
        csr_col[offsets[r.y] + (int)(rk >> 16)]     = (u16)c.y;
    }
}

// ---------------- fused aggregate + MFMA dual-GEMM ----------------
// Block owns 64 rows. Phase 1: gather-mean of the block's own rows from the fp8
// activation image into LDS (slot scheme identical to the standalone aggregate:
// one node per wave at a time, sub=lane>>4 is the edge slot, fl=lane&15 the
// feature octet; fp8 rows are stored post-relu). Phase 2: MFMA dual-GEMM with
// LDS-staged weights (2 K-phases), epilogue bias+residual, writes f16 state
// in-place (row-local) and the NEXT fp8 image (double-buffered vs the gather
// source -> no cross-block hazard).
// LDS: agg area 64 x 136 f16 (17.4KB) is overwritten by the weight tiles
// (2 x 128 x 72 f16 = 36.9KB) after a barrier.
#define WPAD 72    // weight row: 64 k-half + 8 pad  -> per-phase bank-quad spread
#define APAD 136   // agg row: 128 + 8 pad -> ds_read_b128 phases conflict-free

template<int LAYER>   // 0: no relu/res, f16+fp8 out; 1: relu+res, f16+fp8 out; 2: relu+res, f32 out
__global__ __launch_bounds__(256, 4) void sage_fused(
    const u8* __restrict__ h8, const int* __restrict__ offsets,
    const u16* __restrict__ csr, const f16* __restrict__ xb,
    const f16* __restrict__ Wl, const f16* __restrict__ Wr,
    const float* __restrict__ bias, float* __restrict__ outf,
    f16* __restrict__ outh, u8* __restrict__ out8) {
    __shared__ __align__(16) f16 smem[2 * 128 * WPAD];   // 36864 B
    f16 (*aggL)[APAD] = (f16(*)[APAD])smem;
    f16 (*sW)[128][WPAD] = (f16(*)[128][WPAD])smem;

    const int tid  = threadIdx.x;
    const int wave = tid >> 6;
    const int lane = tid & 63;
    const int sub = lane >> 4, fl = lane & 15;
    const int nb0 = blockIdx.x * 64;

    // ---- phase 1: aggregate this block's 64 rows into LDS ----
    for (int v = wave; v < 64; v += 4) {
        int node = nb0 + v;
        int s0 = 0, dg = 0;
        if (node < NN) { s0 = offsets[node]; dg = offsets[node + 1] - s0; }

        float acc[8];
#pragma unroll
        for (int u = 0; u < 8; ++u) acc[u] = 0.f;

        const u8* hp = h8 + fl * 8;

#define UNPACK_ADD(w)                                                  \
    do {                                                               \
        f32x2 p;                                                       \
        p = __builtin_amdgcn_cvt_pk_f32_fp8((w).x, false);             \
        acc[0] += p.x; acc[1] += p.y;                                  \
        p = __builtin_amdgcn_cvt_pk_f32_fp8((w).x, true);              \
        acc[2] += p.x; acc[3] += p.y;                                  \
        p = __builtin_amdgcn_cvt_pk_f32_fp8((w).y, false);             \
        acc[4] += p.x; acc[5] += p.y;                                  \
        p = __builtin_amdgcn_cvt_pk_f32_fp8((w).y, true);              \
        acc[6] += p.x; acc[7] += p.y;                                  \
    } while (0)

        int j = s0 + sub;
        for (int it = dg >> 3; it > 0; --it, j += 8) {
            int c0 = (int)csr[j];
            int c1 = (int)csr[j + 4];
            uint2 w0 = *(const uint2*)(hp + (size_t)c0 * D);
            uint2 w1 = *(const uint2*)(hp + (size_t)c1 * D);
            UNPACK_ADD(w0);
            UNPACK_ADD(w1);
        }
        if (dg & 4) {
            int c = (int)csr[j];
            uint2 w = *(const uint2*)(hp + (size_t)c * D);
            UNPACK_ADD(w);
            j += 4;
        }
        if (sub < (dg & 3)) {
            int c = (int)csr[j];
            uint2 w = *(const uint2*)(hp + (size_t)c * D);
            UNPACK_ADD(w);
        }
#undef UNPACK_ADD

#pragma unroll
        for (int u = 0; u < 8; ++u) {
            acc[u] += __shfl_xor(acc[u], 16, 64);
            acc[u] += __shfl_xor(acc[u], 32, 64);
        }
        if (sub == 0) {
            float inv = 1.f / fmaxf((float)dg, 1.f);
            f16x8 o;
#pragma unroll
            for (int u = 0; u < 8; ++u) o[u] = (f16)(acc[u] * inv);
            *(f16x8*)&aggL[v][fl * 8] = o;
        }
    }
    __syncthreads();

    // ---- phase 2: dual GEMM ----
    const int lm = fl;          // A/C row within wave tile
    const int q  = sub;
    const int mt = nb0 + wave * 16;
    int row = mt + lm;
    int rclamp = (row < NN) ? row : NN - 1;

    f16x8 Aa[4], Ax[4];
    const f16* xrow = xb + (size_t)rclamp * D + q * 8;
#pragma unroll
    for (int ks = 0; ks < 4; ++ks) {
        Aa[ks] = *(const f16x8*)&aggL[wave * 16 + lm][ks * 32 + q * 8];
        f16x8 v = *(const f16x8*)(xrow + ks * 32);
        if (LAYER > 0) {
#pragma unroll
            for (int u = 0; u < 8; ++u) v[u] = (v[u] < (f16)0) ? (f16)0 : v[u];
        }
        Ax[ks] = v;
    }

    f32x4 acc[8];
#pragma unroll
    for (int nt = 0; nt < 8; ++nt) acc[nt] = (f32x4){0.f, 0.f, 0.f, 0.f};

    for (int p = 0; p < 2; ++p) {
        __syncthreads();   // p=0: protects aggL reads; p=1: protects sW reads
#pragma unroll
        for (int it = 0; it < 8; ++it) {
            int idx = tid + it * 256;
            int mat = idx >> 10;
            int n   = (idx >> 3) & 127;
            int c   = idx & 7;
            const f16* W = mat ? Wr : Wl;
            f16x8 v = *(const f16x8*)(W + n * D + p * 64 + c * 8);
            *(f16x8*)&sW[mat][n][c * 8] = v;
        }
        __syncthreads();

#pragma unroll
        for (int nt = 0; nt < 8; ++nt) {
#pragma unroll
            for (int k2 = 0; k2 < 2; ++k2) {
                f16x8 bl = *(const f16x8*)&sW[0][nt * 16 + lm][k2 * 32 + q * 8];
                acc[nt] = __builtin_amdgcn_mfma_f32_16x16x32_f16(Aa[p * 2 + k2], bl, acc[nt], 0, 0, 0);
                f16x8 br = *(const f16x8*)&sW[1][nt * 16 + lm][k2 * 32 + q * 8];
                acc[nt] = __builtin_amdgcn_mfma_f32_16x16x32_f16(Ax[p * 2 + k2], br, acc[nt], 0, 0, 0);
            }
        }
    }

    // epilogue: bias (+ f16 residual from xb). In-place outh==xb is row-local safe.
#pragma unroll
    for (int nt = 0; nt < 8; ++nt) {
        int n = nt * 16 + lm;
        float bval = bias[n];
#pragma unroll
        for (int r = 0; r < 4; ++r) {
            int m = mt + q * 4 + r;
            if (m < NN) {
                size_t idx = (size_t)m * D + n;
                float v = acc[nt][r] + bval;
                if (LAYER > 0) v += (float)xb[idx];
                if (LAYER == 2) {
                    outf[idx] = v;
                } else {
                    outh[idx] = (f16)v;
                    u32 t = __builtin_amdgcn_cvt_pk_fp8_f32(fmaxf(v, 0.f), 0.f, 0, false);
                    out8[idx] = (u8)(t & 0xffu);
                }
            }
        }
    }
}

// ---------------- launch ----------------

extern "C" void kernel_launch(void* const* d_in, const int* in_sizes, int n_in,
                              void* d_out, int out_size, void* d_ws, size_t ws_size,
                              hipStream_t stream) {
    const float* x    = (const float*)d_in[0];
    const int*   erow = (const int*)d_in[1];
    const int*   ecol = (const int*)d_in[2];
    const float* Wl0 = (const float*)d_in[3];
    const float* Wr0 = (const float*)d_in[4];
    const float* b0  = (const float*)d_in[5];
    const float* Wl1 = (const float*)d_in[6];
    const float* Wr1 = (const float*)d_in[7];
    const float* b1  = (const float*)d_in[8];
    const float* Wl2 = (const float*)d_in[9];
    const float* Wr2 = (const float*)d_in[10];
    const float* b2  = (const float*)d_in[11];

    char* ws = (char*)d_ws;
    size_t off = 0;
    auto carve = [&](size_t bytes) -> void* {
        void* p = ws + off;
        off = (off + bytes + 255) & ~(size_t)255;
        return p;
    };
    int*   deg     = (int*)carve((size_t)NN * 4);
    int*   offsets = (int*)carve((size_t)(NN + 1) * 4);
    u16*   rank    = (u16*)carve((size_t)NE * 2);
    u16*   csr_col = (u16*)carve((size_t)NE * 2);
    f16*   xf      = (f16*)carve((size_t)NN * D * 2);
    f16*   x1      = (f16*)carve((size_t)NN * D * 2);
    u8*    xf8     = (u8*)carve((size_t)NN * D);
    u8*    h8a     = (u8*)carve((size_t)NN * D);
    u8*    h8b     = (u8*)carve((size_t)NN * D);
    f16*   wl0 = (f16*)carve(D * D * 2); f16* wr0 = (f16*)carve(D * D * 2);
    f16*   wl1 = (f16*)carve(D * D * 2); f16* wr1 = (f16*)carve(D * D * 2);
    f16*   wl2 = (f16*)carve(D * D * 2); f16* wr2 = (f16*)carve(D * D * 2);
    (void)ws_size; (void)in_sizes; (void)n_in; (void)out_size;

    float* outp = (float*)d_out;

    // prep: converts + deg zero (6250 + 96 + 196 blocks)
    prep<<<6542, 256, 0, stream>>>(x, xf, xf8, Wl0, Wr0, Wl1, Wr1, Wl2, Wr2,
                                   wl0, wr0, wl1, wr1, wl2, wr2, deg);

    // CSR build (2 edges per thread; single-kernel scan)
    const int e2 = NE / 2;
    count_deg_rank<<<(e2 + 255) / 256, 256, 0, stream>>>(erow, deg, rank, e2);
    scan_offsets<<<(NN + 1023) / 1024, 1024, 0, stream>>>(deg, offsets, NN);
    fill_csr<<<(e2 + 255) / 256, 256, 0, stream>>>(erow, ecol, rank, offsets, csr_col, e2);

    const int ggrid = (NN + 63) / 64;       // 782

    // layer 0: x1 = agg(x)@Wl0^T + x@Wr0^T + b0; h8a = fp8(relu(x1))
    sage_fused<0><<<ggrid, 256, 0, stream>>>(xf8, offsets, csr_col, xf,
                                             wl0, wr0, b0, nullptr, x1, h8a);
    // layer 1: x1 += agg/self of relu(x1); h8b = fp8(relu(new x1))
    sage_fused<1><<<ggrid, 256, 0, stream>>>(h8a, offsets, csr_col, x1,
                                             wl1, wr1, b1, nullptr, x1, h8b);
    // layer 2: out(f32) = agg/self of relu(x1) + residual
    sage_fused<2><<<ggrid, 256, 0, stream>>>(h8b, offsets, csr_col, x1,
                                             wl2, wr2, b2, outp, nullptr, nullptr);
}

// Round 8
// 282.949 us; speedup vs baseline: 1.1423x; 1.1423x over previous
//
#include <hip/hip_runtime.h>

#define NN 50000
#define NE 800000
#define D  128

typedef _Float16 f16;
typedef _Float16 f16x4 __attribute__((ext_vector_type(4)));
typedef _Float16 f16x8 __attribute__((ext_vector_type(8)));
typedef float f32x4 __attribute__((ext_vector_type(4)));
typedef float f32x2 __attribute__((ext_vector_type(2)));
typedef unsigned short u16;
typedef unsigned int u32;
typedef unsigned char u8;

// ---------------- prep: f32->f16 + f32->fp8 converts + deg zeroing ----------------
// blocks [0,6250): x -> xf (f16) and xf8 (fp8); [6250,6346): 6 weight mats; rest: zero deg
__global__ __launch_bounds__(256) void prep(
    const float* __restrict__ x, f16* __restrict__ xf, u8* __restrict__ xf8,
    const float* w0, const float* w1, const float* w2,
    const float* w3, const float* w4, const float* w5,
    f16* d0, f16* d1, f16* d2, f16* d3, f16* d4, f16* d5,
    int* __restrict__ deg) {
    int b = blockIdx.x;
    if (b < 6250) {
        int i = b * 256 + threadIdx.x;
        float4 v = ((const float4*)x)[i];
        f16x4 o = {(f16)v.x, (f16)v.y, (f16)v.z, (f16)v.w};
        ((f16x4*)xf)[i] = o;
        u32 lo = __builtin_amdgcn_cvt_pk_fp8_f32(v.x, v.y, 0, false);
        u32 pk = __builtin_amdgcn_cvt_pk_fp8_f32(v.z, v.w, lo, true);
        ((u32*)xf8)[i] = pk;
    } else if (b < 6346) {
        int wb = b - 6250;
        int mat = wb >> 4;
        const float* s; f16* d;
        switch (mat) {
            case 0: s = w0; d = d0; break; case 1: s = w1; d = d1; break;
            case 2: s = w2; d = d2; break; case 3: s = w3; d = d3; break;
            case 4: s = w4; d = d4; break; default: s = w5; d = d5; break;
        }
        int i = (wb & 15) * 256 + threadIdx.x;   // 0..4095 float4
        float4 v = ((const float4*)s)[i];
        f16x4 o = {(f16)v.x, (f16)v.y, (f16)v.z, (f16)v.w};
        ((f16x4*)d)[i] = o;
    } else {
        int i = (b - 6346) * 256 + threadIdx.x;
        if (i < NN) deg[i] = 0;
    }
}

// ---------------- CSR build (2 edges/thread; single-kernel scan) ----------------

__global__ __launch_bounds__(256) void count_deg_rank(
    const int* __restrict__ row, int* __restrict__ deg, u16* __restrict__ rank, int e2) {
    int i = blockIdx.x * blockDim.x + threadIdx.x;
    if (i < e2) {
        int2 r = ((const int2*)row)[i];
        unsigned ra = (unsigned)atomicAdd(&deg[r.x], 1);
        unsigned rb = (unsigned)atomicAdd(&deg[r.y], 1);
        ((unsigned*)rank)[i] = (ra & 0xffffu) | (rb << 16);
    }
}

// single-kernel scan: each block redundantly reduces its prefix (deg is L2-resident)
__global__ void scan_offsets(const int* __restrict__ deg, int* __restrict__ offsets, int n) {
    __shared__ int s[1024];
    int lim = blockIdx.x << 10;
    int a = 0;
    for (int i = threadIdx.x; i < lim; i += 1024) a += deg[i];
    s[threadIdx.x] = a;
    __syncthreads();
    for (int off = 512; off > 0; off >>= 1) {
        if (threadIdx.x < off) s[threadIdx.x] += s[threadIdx.x + off];
        __syncthreads();
    }
    int base = s[0];
    __syncthreads();
    int i = lim + threadIdx.x;
    int dv = (i < n) ? deg[i] : 0;
    s[threadIdx.x] = dv;
    __syncthreads();
    for (int off = 1; off < 1024; off <<= 1) {
        int t = (threadIdx.x >= (unsigned)off) ? s[threadIdx.x - off] : 0;
        __syncthreads();
        s[threadIdx.x] += t;
        __syncthreads();
    }
    if (i < n) {
        offsets[i + 1] = s[threadIdx.x] + base;
        if (i == 0) offsets[0] = 0;
    }
}

__global__ __launch_bounds__(256) void fill_csr(
    const int* __restrict__ row, const int* __restrict__ col,
    const u16* __restrict__ rank, const int* __restrict__ offsets,
    u16* __restrict__ csr_col, int e2) {
    int i = blockIdx.x * blockDim.x + threadIdx.x;
    if (i < e2) {
        int2 r = ((const int2*)row)[i];
        int2 c = ((const int2*)col)[i];
        unsigned rk = ((const unsigned*)rank)[i];
        csr_col[offsets[r.x] + (int)(rk & 0xffffu)] = (u16)c.x;
        csr_col[offsets[r.y] + (int)(rk >> 16)]     = (u16)c.y;
    }
}

// ---------------- mean aggregation (fp8 gather, fp32 accumulate) ----------------
// One wave per node (12500 blocks -> ~48 blocks/CU oversubscription hides gather
// latency; round-7 fusion at 3 blocks/CU proved this is required).
// sub = lane>>4 is the edge slot (4 edges/load-instr), fl = lane&15 the feature
// octet: 8B fp8 per lane -> 128B/row, 512B/wave-instr. fp8 rows are post-relu.
__global__ __launch_bounds__(256) void aggregate_f8(
    const u8* __restrict__ h8, const int* __restrict__ offsets,
    const u16* __restrict__ csr, f16* __restrict__ agg) {
    int node = blockIdx.x * 4 + (threadIdx.x >> 6);
    int lane = threadIdx.x & 63;
    int sub = lane >> 4, fl = lane & 15;
    int s0 = offsets[node], e0 = offsets[node + 1];
    int deg = e0 - s0;

    float acc[8];
#pragma unroll
    for (int u = 0; u < 8; ++u) acc[u] = 0.f;

    const u8* hp = h8 + fl * 8;

#define UNPACK_ADD(w)                                                  \
    do {                                                               \
        f32x2 p;                                                       \
        p = __builtin_amdgcn_cvt_pk_f32_fp8((w).x, false);             \
        acc[0] += p.x; acc[1] += p.y;                                  \
        p = __builtin_amdgcn_cvt_pk_f32_fp8((w).x, true);              \
        acc[2] += p.x; acc[3] += p.y;                                  \
        p = __builtin_amdgcn_cvt_pk_f32_fp8((w).y, false);             \
        acc[4] += p.x; acc[5] += p.y;                                  \
        p = __builtin_amdgcn_cvt_pk_f32_fp8((w).y, true);              \
        acc[6] += p.x; acc[7] += p.y;                                  \
    } while (0)

    int j = s0 + sub;
    for (int it = deg >> 3; it > 0; --it, j += 8) {
        int c0 = (int)csr[j];
        int c1 = (int)csr[j + 4];
        uint2 w0 = *(const uint2*)(hp + (size_t)c0 * D);
        uint2 w1 = *(const uint2*)(hp + (size_t)c1 * D);
        UNPACK_ADD(w0);
        UNPACK_ADD(w1);
    }
    if (deg & 4) {
        int c = (int)csr[j];
        uint2 w = *(const uint2*)(hp + (size_t)c * D);
        UNPACK_ADD(w);
        j += 4;
    }
    if (sub < (deg & 3)) {
        int c = (int)csr[j];
        uint2 w = *(const uint2*)(hp + (size_t)c * D);
        UNPACK_ADD(w);
    }
#undef UNPACK_ADD

    // reduce across the 4 edge slots (lanes l, l^16, l^32, l^48)
#pragma unroll
    for (int u = 0; u < 8; ++u) {
        acc[u] += __shfl_xor(acc[u], 16, 64);
        acc[u] += __shfl_xor(acc[u], 32, 64);
    }
    if (sub == 0) {
        float inv = 1.f / fmaxf((float)deg, 1.f);
        f16x8 o;
#pragma unroll
        for (int u = 0; u < 8; ++u) o[u] = (f16)(acc[u] * inv);
        *((f16x8*)(agg + (size_t)node * D) + fl) = o;
    }
}

// ---------------- MFMA dual-GEMM, LDS-staged weights ----------------
// out[m][n] = sum_k agg[m][k]*Wl[n][k] + relu?(x[m][k])*Wr[n][k] + b[n] (+ x[m][n])
// When !OUT_F32 also writes out8 = fp8(relu(out)) for the next layer's gather.
#define WPAD 72   // 64 + 8 f16 pad -> 144B row stride, <=2-way bank aliasing

template<int RELU_X, int ADD_RES, int OUT_F32>
__global__ __launch_bounds__(256, 4) void sage_gemm_mfma(
    const f16* __restrict__ aggb, const f16* __restrict__ xb,
    const f16* __restrict__ Wl, const f16* __restrict__ Wr,
    const float* __restrict__ bias, float* __restrict__ outf,
    f16* __restrict__ outh, u8* __restrict__ out8) {
    __shared__ f16 sW[2][128][WPAD];   // 36864 B

    const int tid  = threadIdx.x;
    const int wave = tid >> 6;
    const int lane = tid & 63;
    const int lm = lane & 15;
    const int q  = lane >> 4;
    const int mt = blockIdx.x * 64 + wave * 16;

    int row = mt + lm;
    int rclamp = (row < NN) ? row : NN - 1;

    // A fragments (full K), relu on x inline
    f16x8 Aa[4], Ax[4];
    const f16* arow = aggb + (size_t)rclamp * D + q * 8;
    const f16* xrow = xb  + (size_t)rclamp * D + q * 8;
#pragma unroll
    for (int ks = 0; ks < 4; ++ks) {
        Aa[ks] = *(const f16x8*)(arow + ks * 32);
        f16x8 v = *(const f16x8*)(xrow + ks * 32);
        if (RELU_X) {
#pragma unroll
            for (int u = 0; u < 8; ++u) v[u] = (v[u] < (f16)0) ? (f16)0 : v[u];
        }
        Ax[ks] = v;
    }

    f32x4 acc[8];
#pragma unroll
    for (int nt = 0; nt < 8; ++nt) acc[nt] = (f32x4){0.f, 0.f, 0.f, 0.f};

    for (int p = 0; p < 2; ++p) {
        __syncthreads();
        // stage Wl/Wr K-half: 2 mats x 128 n x 8 chunks of 16B = 2048 chunks
#pragma unroll
        for (int it = 0; it < 8; ++it) {
            int idx = tid + it * 256;
            int mat = idx >> 10;
            int n   = (idx >> 3) & 127;
            int c   = idx & 7;
            const f16* W = mat ? Wr : Wl;
            f16x8 v = *(const f16x8*)(W + n * D + p * 64 + c * 8);
            *(f16x8*)&sW[mat][n][c * 8] = v;
        }
        __syncthreads();

#pragma unroll
        for (int nt = 0; nt < 8; ++nt) {
#pragma unroll
            for (int k2 = 0; k2 < 2; ++k2) {
                f16x8 bl = *(const f16x8*)&sW[0][nt * 16 + lm][k2 * 32 + q * 8];
                acc[nt] = __builtin_amdgcn_mfma_f32_16x16x32_f16(Aa[p * 2 + k2], bl, acc[nt], 0, 0, 0);
                f16x8 br = *(const f16x8*)&sW[1][nt * 16 + lm][k2 * 32 + q * 8];
                acc[nt] = __builtin_amdgcn_mfma_f32_16x16x32_f16(Ax[p * 2 + k2], br, acc[nt], 0, 0, 0);
            }
        }
    }

    // epilogue: bias (+ f16 residual from xb). In-place outh==xb is safe:
    // each (m,n) is read & written by exactly one lane, rows owned by this wave.
#pragma unroll
    for (int nt = 0; nt < 8; ++nt) {
        int n = nt * 16 + lm;
        float bval = bias[n];
#pragma unroll
        for (int r = 0; r < 4; ++r) {
            int m = mt + q * 4 + r;
            if (m < NN) {
                size_t idx = (size_t)m * D + n;
                float v = acc[nt][r] + bval;
                if (ADD_RES) v += (float)xb[idx];
                if (OUT_F32) {
                    outf[idx] = v;
                } else {
                    outh[idx] = (f16)v;
                    u32 t = __builtin_amdgcn_cvt_pk_fp8_f32(fmaxf(v, 0.f), 0.f, 0, false);
                    out8[idx] = (u8)(t & 0xffu);
                }
            }
        }
    }
}

// ---------------- launch ----------------

extern "C" void kernel_launch(void* const* d_in, const int* in_sizes, int n_in,
                              void* d_out, int out_size, void* d_ws, size_t ws_size,
                              hipStream_t stream) {
    const float* x    = (const float*)d_in[0];
    const int*   erow = (const int*)d_in[1];
    const int*   ecol = (const int*)d_in[2];
    const float* Wl0 = (const float*)d_in[3];
    const float* Wr0 = (const float*)d_in[4];
    const float* b0  = (const float*)d_in[5];
    const float* Wl1 = (const float*)d_in[6];
    const float* Wr1 = (const float*)d_in[7];
    const float* b1  = (const float*)d_in[8];
    const float* Wl2 = (const float*)d_in[9];
    const float* Wr2 = (const float*)d_in[10];
    const float* b2  = (const float*)d_in[11];

    char* ws = (char*)d_ws;
    size_t off = 0;
    auto carve = [&](size_t bytes) -> void* {
        void* p = ws + off;
        off = (off + bytes + 255) & ~(size_t)255;
        return p;
    };
    int*   deg     = (int*)carve((size_t)NN * 4);
    int*   offsets = (int*)carve((size_t)(NN + 1) * 4);
    u16*   rank    = (u16*)carve((size_t)NE * 2);
    u16*   csr_col = (u16*)carve((size_t)NE * 2);
    f16*   xf      = (f16*)carve((size_t)NN * D * 2);
    f16*   x1      = (f16*)carve((size_t)NN * D * 2);
    f16*   aggb    = (f16*)carve((size_t)NN * D * 2);
    u8*    xf8     = (u8*)carve((size_t)NN * D);
    u8*    x1f8    = (u8*)carve((size_t)NN * D);
    f16*   wl0 = (f16*)carve(D * D * 2); f16* wr0 = (f16*)carve(D * D * 2);
    f16*   wl1 = (f16*)carve(D * D * 2); f16* wr1 = (f16*)carve(D * D * 2);
    f16*   wl2 = (f16*)carve(D * D * 2); f16* wr2 = (f16*)carve(D * D * 2);
    (void)ws_size; (void)in_sizes; (void)n_in; (void)out_size;

    float* outp = (float*)d_out;

    // prep: converts + deg zero (6250 + 96 + 196 blocks)
    prep<<<6542, 256, 0, stream>>>(x, xf, xf8, Wl0, Wr0, Wl1, Wr1, Wl2, Wr2,
                                   wl0, wr0, wl1, wr1, wl2, wr2, deg);

    // CSR build (2 edges per thread; single-kernel scan)
    const int e2 = NE / 2;
    count_deg_rank<<<(e2 + 255) / 256, 256, 0, stream>>>(erow, deg, rank, e2);
    scan_offsets<<<(NN + 1023) / 1024, 1024, 0, stream>>>(deg, offsets, NN);
    fill_csr<<<(e2 + 255) / 256, 256, 0, stream>>>(erow, ecol, rank, offsets, csr_col, e2);

    const int agrid = NN / 4;               // 12500, exact
    const int ggrid = (NN + 63) / 64;       // 782

    // layer 0: x1 = agg(x)@Wl0^T + x@Wr0^T + b0; x1f8 = fp8(relu(x1))
    aggregate_f8<<<agrid, 256, 0, stream>>>(xf8, offsets, csr_col, aggb);
    sage_gemm_mfma<0, 0, 0><<<ggrid, 256, 0, stream>>>(aggb, xf, wl0, wr0, b0,
                                                       nullptr, x1, x1f8);
    // layer 1: x1 = agg(relu(x1))@Wl1^T + relu(x1)@Wr1^T + b1 + x1  (in place)
    aggregate_f8<<<agrid, 256, 0, stream>>>(x1f8, offsets, csr_col, aggb);
    sage_gemm_mfma<1, 1, 0><<<ggrid, 256, 0, stream>>>(aggb, x1, wl1, wr1, b1,
                                                       nullptr, x1, x1f8);
    // layer 2: out = agg(relu(x1))@Wl2^T + relu(x1)@Wr2^T + b2 + x1  (fp32)
    aggregate_f8<<<agrid, 256, 0, stream>>>(x1f8, offsets, csr_col, aggb);
    sage_gemm_mfma<1, 1, 1><<<ggrid, 256, 0, stream>>>(aggb, x1, wl2, wr2, b2,
                                                       outp, nullptr, nullptr);
}